// Round 5
// baseline (422.654 us; speedup 1.0000x reference)
//
#include <hip/hip_runtime.h>
#include <hip/hip_cooperative_groups.h>
#include <hip/hip_bf16.h>

#define NN 50000
#define EE 800000
#define DD 128
#define CB 196      // coarse buckets of 256 nodes (196*256 = 50176)
#define NFB 1563    // fine buckets of 32 nodes (mega grid)
#define GB 256      // cooperative grid blocks (1 per CU)
#define GT 512      // threads per cooperative block
#define ECH 3125    // edges per chunk = EE/GB exactly

typedef __attribute__((ext_vector_type(8))) short bf16x8;
typedef __attribute__((ext_vector_type(4))) float f32x4;

namespace cg = cooperative_groups;

static __device__ __forceinline__ unsigned short f2bf(float f) {
  union { float f; unsigned u; } v; v.f = f;
  unsigned r = v.u + 0x7FFFu + ((v.u >> 16) & 1u);
  return (unsigned short)(r >> 16);
}
static __device__ __forceinline__ float bf2f(unsigned short h) {
  union { unsigned u; float f; } v; v.u = ((unsigned)h) << 16;
  return v.f;
}

// One cooperative kernel does ALL preprocessing in 4 phases:
//  A: stage 3125-edge chunk records in LDS, per-chunk coarse histogram ->
//     hist[cb][256] (transposed), x->bf16 xb, W->bf16 Wt.
//  B: bucket-sort the LDS-resident chunk into coarse-bucket runs of pairs
//     (bases self-computed from hist column sums + one packed scan; NO
//     global atomics).
//  C: blocks <196: per-bucket fine histogram -> deg/dinv/rowStart, scatter
//     src -> srcU16.
//  D: grid-wide stream xs = dinv * xb.
// LDS (33.3 KB) is phase-aliased; rec[] survives A->B.
__global__ __launch_bounds__(GT) void k_fused(
    const int* __restrict__ src, const int* __restrict__ dst,
    const float* __restrict__ x, const float* __restrict__ Wg,
    const float* __restrict__ Wl, int* __restrict__ hist,
    int* __restrict__ bucketBase, int* __restrict__ bucketTot,
    unsigned int* __restrict__ pairs, unsigned short* __restrict__ srcU16,
    int* __restrict__ deg, float* __restrict__ dinv,
    int* __restrict__ rowStart, unsigned short* __restrict__ Wt,
    unsigned short* __restrict__ xb, unsigned short* __restrict__ xs) {
  __shared__ unsigned int smem[8320];  // 33.3 KB, aliased per phase
  cg::grid_group grid = cg::this_grid();
  int blk = blockIdx.x, t = threadIdx.x;

  // ---------------- Phase A ----------------
  unsigned int* rec = smem;              // [0,3125)  (survives into phase B)
  int* cnt = (int*)(smem + 6272);        // [6272,6468) aliases phase-B sTo
  for (int i = t; i < CB; i += GT) cnt[i] = 0;
  __syncthreads();
  int e0 = blk * ECH;
  for (int i = t; i < ECH; i += GT) {
    int d = dst[e0 + i], s = src[e0 + i];
    rec[i] = (unsigned)s | ((unsigned)(d & 255) << 16) |
             ((unsigned)(d >> 8) << 24);
    atomicAdd(&cnt[d >> 8], 1);
  }
  {  // W transpose+convert: 64*512 == DD*256 exactly (blocks 0..63)
    int i = blk * GT + t;
    if (i < DD * 256) {
      int n = i >> 8, k = i & 255;
      float v = (k < 128) ? Wg[k * DD + n] : Wl[(k - 128) * DD + n];
      Wt[i] = f2bf(v);
    }
  }
  {  // x -> bf16 xb, grid-stride
    const float4* x4 = (const float4*)x;
    ushort4* xb4 = (ushort4*)xb;
    for (int i = blk * GT + t; i < NN * 32; i += GB * GT) {
      float4 v = x4[i];
      ushort4 o;
      o.x = f2bf(v.x); o.y = f2bf(v.y); o.z = f2bf(v.z); o.w = f2bf(v.w);
      xb4[i] = o;
    }
  }
  __syncthreads();
  for (int i = t; i < CB; i += GT) hist[i * GB + blk] = cnt[i];
  __threadfence();
  grid.sync();

  // ---------------- Phase B ----------------
  unsigned int* sorted = smem + 3136;    // [3136,6261)
  int* sTo = (int*)(smem + 6272);        // [2][196]
  int* sCh = (int*)(smem + 6664);
  int* sOw = (int*)(smem + 7056);
  unsigned int* sc = smem + 7448;        // [256]
  int* cur = (int*)(smem + 7704);        // [196]
  int* gofs = (int*)(smem + 7900);       // [196]
  {
    int q = t & 255, h = t >> 8;
    if (q < CB) {
      const uint4* hp = (const uint4*)(hist + q * GB + h * 128);
      int c0 = h * 128;
      int to = 0, ch = 0, ow = 0;
#pragma unroll 8
      for (int v = 0; v < 32; ++v) {  // 32 uint4 = 128 ints per half-row
        uint4 hv = hp[v];
        int c = c0 + v * 4;
        int a0 = (int)hv.x, a1 = (int)hv.y, a2 = (int)hv.z, a3 = (int)hv.w;
        to += a0 + a1 + a2 + a3;
        ch += (c + 0 < blk ? a0 : 0) + (c + 1 < blk ? a1 : 0) +
              (c + 2 < blk ? a2 : 0) + (c + 3 < blk ? a3 : 0);
        ow += (c + 0 == blk ? a0 : 0) + (c + 1 == blk ? a1 : 0) +
              (c + 2 == blk ? a2 : 0) + (c + 3 == blk ? a3 : 0);
      }
      sTo[h * CB + q] = to; sCh[h * CB + q] = ch; sOw[h * CB + q] = ow;
    }
  }
  __syncthreads();
  int totv = 0, chpv = 0, ownv = 0;
  if (t < CB) {
    totv = sTo[t] + sTo[CB + t];
    chpv = sCh[t] + sCh[CB + t];
    ownv = sOw[t] + sOw[CB + t];
  }
  // packed scan: (tot<<12)|own. sum(tot)=800000<2^20, sum(own)=3125<2^12.
  if (t < 256) sc[t] = (t < CB) ? (((unsigned)totv << 12) | (unsigned)ownv) : 0u;
  for (int off = 1; off < 256; off <<= 1) {
    __syncthreads();
    unsigned tmp = (t < 256 && t >= off) ? sc[t - off] : 0u;
    __syncthreads();
    if (t < 256 && t >= off) sc[t] += tmp;
  }
  __syncthreads();
  if (t < CB) {
    unsigned v = sc[t];
    int gb = (int)(v >> 12) - totv;        // bucket global base
    int lo = (int)(v & 4095u) - ownv;      // local sorted base in this chunk
    cur[t] = lo;
    gofs[t] = gb + chpv - lo;              // pairs addr of sorted slot i
    if (blk == 0) { bucketBase[t] = gb; bucketTot[t] = totv; }
  }
  __syncthreads();
  for (int i = t; i < ECH; i += GT) {      // LDS counting-sort
    unsigned r = rec[i];
    int p = atomicAdd(&cur[r >> 24], 1);
    sorted[p] = r;
  }
  __syncthreads();
  for (int i = t; i < ECH; i += GT) {      // coalesced run write-out
    unsigned r = sorted[i];
    pairs[gofs[r >> 24] + i] = r;
  }
  __threadfence();
  grid.sync();

  // ---------------- Phase C (blocks < CB) ----------------
  int* ldeg = (int*)smem;                  // [0,256)
  int* lscan = (int*)smem + 256;
  int* lcur = (int*)smem + 512;
  if (blk < CB) {
    int n0 = blk << 8;
    int nloc = NN - n0; if (nloc > 256) nloc = 256;
    int start = bucketBase[blk], cntb = bucketTot[blk];
    if (t < 256) ldeg[t] = 0;
    __syncthreads();
    for (int i = t; i < cntb; i += GT)
      atomicAdd(&ldeg[(pairs[start + i] >> 16) & 255], 1);
    __syncthreads();
    int dg = (t < 256) ? ldeg[t] : 0;
    if (t < 256) lscan[t] = dg;
    for (int off = 1; off < 256; off <<= 1) {
      __syncthreads();
      int tmp = (t < 256 && t >= off) ? lscan[t - off] : 0;
      __syncthreads();
      if (t < 256 && t >= off) lscan[t] += tmp;
    }
    __syncthreads();
    if (t < 256) {
      int rs = start + lscan[t] - dg;
      lcur[t] = rs;
      if (t < nloc) {
        deg[n0 + t] = dg;
        dinv[n0 + t] = rsqrtf((float)(dg + 1));
        rowStart[n0 + t] = rs;
      }
    }
    __syncthreads();
    for (int i = t; i < cntb; i += GT) {
      unsigned pr = pairs[start + i];
      int pos = atomicAdd(&lcur[(pr >> 16) & 255], 1);
      srcU16[pos] = (unsigned short)(pr & 0xFFFFu);
    }
  }
  __threadfence();
  grid.sync();

  // ---------------- Phase D: xs = dinv * xb, grid-wide ----------------
  for (int i = blk * GT + t; i < NN * 16; i += GB * GT) {
    int row = i >> 4;
    float di = dinv[row];
    bf16x8 v = *(const bf16x8*)(xb + (size_t)i * 8);
    bf16x8 o;
#pragma unroll
    for (int k = 0; k < 8; k++) o[k] = (short)f2bf(bf2f((unsigned short)v[k]) * di);
    *(bf16x8*)(xs + (size_t)i * 8) = o;
  }
}

// Gather a node's CSR range into acc[8] (lane slice r*8), 8 rows in flight.
static __device__ __forceinline__ void gather16(
    const unsigned short* __restrict__ xs, const unsigned short* __restrict__ srcU16,
    int js, int cnt, int r, int srcLaneBase, float* acc) {
  for (int base = 0; base < cnt; base += 16) {
    int idx = (base + r < cnt) ? (int)srcU16[js + base + r] : 0;
    int m = cnt - base; if (m > 16) m = 16;
    int j = 0;
    for (; j + 8 <= m; j += 8) {
      int s0 = __shfl(idx, srcLaneBase + j);
      int s1 = __shfl(idx, srcLaneBase + j + 1);
      int s2 = __shfl(idx, srcLaneBase + j + 2);
      int s3 = __shfl(idx, srcLaneBase + j + 3);
      int s4 = __shfl(idx, srcLaneBase + j + 4);
      int s5 = __shfl(idx, srcLaneBase + j + 5);
      int s6 = __shfl(idx, srcLaneBase + j + 6);
      int s7 = __shfl(idx, srcLaneBase + j + 7);
      bf16x8 v0 = *(const bf16x8*)(xs + (size_t)s0 * DD + r * 8);
      bf16x8 v1 = *(const bf16x8*)(xs + (size_t)s1 * DD + r * 8);
      bf16x8 v2 = *(const bf16x8*)(xs + (size_t)s2 * DD + r * 8);
      bf16x8 v3 = *(const bf16x8*)(xs + (size_t)s3 * DD + r * 8);
      bf16x8 v4 = *(const bf16x8*)(xs + (size_t)s4 * DD + r * 8);
      bf16x8 v5 = *(const bf16x8*)(xs + (size_t)s5 * DD + r * 8);
      bf16x8 v6 = *(const bf16x8*)(xs + (size_t)s6 * DD + r * 8);
      bf16x8 v7 = *(const bf16x8*)(xs + (size_t)s7 * DD + r * 8);
#pragma unroll
      for (int k = 0; k < 8; k++) acc[k] += bf2f((unsigned short)v0[k]);
#pragma unroll
      for (int k = 0; k < 8; k++) acc[k] += bf2f((unsigned short)v1[k]);
#pragma unroll
      for (int k = 0; k < 8; k++) acc[k] += bf2f((unsigned short)v2[k]);
#pragma unroll
      for (int k = 0; k < 8; k++) acc[k] += bf2f((unsigned short)v3[k]);
#pragma unroll
      for (int k = 0; k < 8; k++) acc[k] += bf2f((unsigned short)v4[k]);
#pragma unroll
      for (int k = 0; k < 8; k++) acc[k] += bf2f((unsigned short)v5[k]);
#pragma unroll
      for (int k = 0; k < 8; k++) acc[k] += bf2f((unsigned short)v6[k]);
#pragma unroll
      for (int k = 0; k < 8; k++) acc[k] += bf2f((unsigned short)v7[k]);
    }
    for (; j < m; j++) {
      int s = __shfl(idx, srcLaneBase + j);
      bf16x8 v = *(const bf16x8*)(xs + (size_t)s * DD + r * 8);
#pragma unroll
      for (int k = 0; k < 8; k++) acc[k] += bf2f((unsigned short)v[k]);
    }
  }
}

// One block per 32-node bucket, 512 threads: 32 groups x 1 node gather,
// then waves 0-1 run the MFMA [agg|x]@[Wg;Wl] + bias + LayerNorm epilogue.
__global__ __launch_bounds__(512) void k_mega4(
    const unsigned short* __restrict__ xs, const unsigned short* __restrict__ xb,
    const int* __restrict__ rowStart, const int* __restrict__ deg,
    const unsigned short* __restrict__ srcU16, const float* __restrict__ dinv,
    const unsigned short* __restrict__ Wt, const float* __restrict__ bgcn,
    const float* __restrict__ lnw, const float* __restrict__ lnb,
    float* __restrict__ out) {
  __shared__ unsigned short abuf[32 * 136];  // 8.7 KB
  int b = blockIdx.x, t = threadIdx.x;
  int n0 = b * 32;
  int g = t >> 4, r = t & 15;
  int lane = t & 63;
  int srcLaneBase = lane & 48;
  int node = n0 + g;
  bool valid = (node < NN);
  int nc = valid ? node : (NN - 1);
  float acc[8];
  {  // self-loop init from pre-scaled xs
    bf16x8 va = *(const bf16x8*)(xs + (size_t)nc * DD + r * 8);
#pragma unroll
    for (int k = 0; k < 8; k++) acc[k] = bf2f((unsigned short)va[k]);
  }
  int js = valid ? rowStart[nc] : 0;
  int cnt = valid ? deg[nc] : 0;
  gather16(xs, srcU16, js, cnt, r, srcLaneBase, acc);
  {
    float d = dinv[nc];
    bf16x8 o;
#pragma unroll
    for (int k = 0; k < 8; k++) o[k] = valid ? (short)f2bf(acc[k] * d) : (short)0;
    *(bf16x8*)&abuf[g * 136 + r * 8] = o;
  }
  __syncthreads();
  if (t < 128) {  // waves 0,1: two 16-row MFMA tiles + fused LayerNorm
    int w = t >> 6, lane2 = t & 63;
    int quad = lane2 >> 4, rr = lane2 & 15;
    int mloc = w * 16 + rr;
    int rowA = n0 + mloc; int rc = (rowA < NN) ? rowA : (NN - 1);
    f32x4 zero = {0.f, 0.f, 0.f, 0.f};
    f32x4 macc[8];
#pragma unroll
    for (int i = 0; i < 8; i++) macc[i] = zero;
#pragma unroll
    for (int ks = 0; ks < 8; ks++) {
      bf16x8 a;
      if (ks < 4) a = *(const bf16x8*)&abuf[mloc * 136 + ks * 32 + quad * 8];
      else        a = *(const bf16x8*)(xb + (size_t)rc * DD + (ks - 4) * 32 + quad * 8);
#pragma unroll
      for (int nt = 0; nt < 8; nt++) {
        bf16x8 bb = *(const bf16x8*)(Wt + (size_t)(nt * 16 + rr) * 256 + ks * 32 + quad * 8);
        macc[nt] = __builtin_amdgcn_mfma_f32_16x16x32_bf16(a, bb, macc[nt], 0, 0, 0);
      }
    }
    float bg[8], lw[8], lb[8];
#pragma unroll
    for (int nt = 0; nt < 8; nt++) {
      int col = nt * 16 + rr;
      bg[nt] = bgcn[col] + 1e-6f;
      lw[nt] = lnw[col];
      lb[nt] = lnb[col];
    }
#pragma unroll
    for (int reg = 0; reg < 4; reg++) {
      float y[8];
      float s1 = 0.f, s2 = 0.f;
#pragma unroll
      for (int nt = 0; nt < 8; nt++) {
        y[nt] = macc[nt][reg] + bg[nt];
        s1 += y[nt];
        s2 += y[nt] * y[nt];
      }
#pragma unroll
      for (int off = 1; off < 16; off <<= 1) {
        s1 += __shfl_xor(s1, off);
        s2 += __shfl_xor(s2, off);
      }
      float mu = s1 * (1.0f / 128.0f);
      float var = s2 * (1.0f / 128.0f) - mu * mu;
      float inv = rsqrtf(var + 1e-5f);
      int row = n0 + w * 16 + quad * 4 + reg;
      if (row < NN) {
#pragma unroll
        for (int nt = 0; nt < 8; nt++) {
          out[(size_t)row * DD + nt * 16 + rr] = (y[nt] - mu) * inv * lw[nt] + lb[nt];
        }
      }
    }
  }
}

extern "C" void kernel_launch(void* const* d_in, const int* in_sizes, int n_in,
                              void* d_out, int out_size, void* d_ws, size_t ws_size,
                              hipStream_t stream) {
  const int* adj = (const int*)d_in[0];
  const float* x = (const float*)d_in[1];
  const float* Wg = (const float*)d_in[2];
  const float* bg = (const float*)d_in[3];
  const float* Wl = (const float*)d_in[4];
  const float* lw = (const float*)d_in[5];
  const float* lb = (const float*)d_in[6];
  const int* srcp = adj;
  const int* dstp = adj + EE;
  float* out = (float*)d_out;

  char* ws = (char*)d_ws;
  size_t off = 0;
  auto alloc = [&](size_t bytes) -> void* {
    void* p = ws + off;
    off += (bytes + 255) & ~(size_t)255;
    return p;
  };
  int* hist = (int*)alloc((size_t)CB * GB * 4);   // transposed [cb][chunk]
  int* bucketBase = (int*)alloc((size_t)256 * 4);
  int* bucketTot = (int*)alloc((size_t)256 * 4);
  unsigned int* pairs = (unsigned int*)alloc((size_t)EE * 4);
  unsigned short* srcU16 = (unsigned short*)alloc((size_t)EE * 2);
  int* deg = (int*)alloc((size_t)NN * 4);
  float* dinv = (float*)alloc((size_t)NN * 4);
  int* rowStart = (int*)alloc((size_t)NN * 4);
  unsigned short* xb = (unsigned short*)alloc((size_t)NN * DD * 2);
  unsigned short* xs = (unsigned short*)alloc((size_t)NN * DD * 2);
  unsigned short* Wt = (unsigned short*)alloc((size_t)DD * 256 * 2);
  (void)ws_size; (void)in_sizes; (void)n_in; (void)out_size;

  void* args[] = {(void*)&srcp, (void*)&dstp, (void*)&x, (void*)&Wg,
                  (void*)&Wl, (void*)&hist, (void*)&bucketBase,
                  (void*)&bucketTot, (void*)&pairs, (void*)&srcU16,
                  (void*)&deg, (void*)&dinv, (void*)&rowStart, (void*)&Wt,
                  (void*)&xb, (void*)&xs};
  hipLaunchCooperativeKernel((const void*)k_fused, dim3(GB), dim3(GT), args, 0,
                             stream);
  k_mega4<<<NFB, 512, 0, stream>>>(xs, xb, rowStart, deg, srcU16, dinv, Wt,
                                   bg, lw, lb, out);
}

// Round 6
// 192.995 us; speedup vs baseline: 2.1900x; 2.1900x over previous
//
#include <hip/hip_runtime.h>
#include <hip/hip_bf16.h>

#define NN 50000
#define EE 800000
#define DD 128
#define CB 196      // coarse buckets of 256 nodes (196*256 = 50176)
#define NFB 1563    // fine buckets of 32 nodes (mega grid)
#define EBLK 2048
#define NEBK 391    // ceil(EE/EBLK)
#define HST 392     // hist row stride (NEBK padded to multiple of 4)

typedef __attribute__((ext_vector_type(8))) short bf16x8;
typedef __attribute__((ext_vector_type(4))) float f32x4;

static __device__ __forceinline__ unsigned short f2bf(float f) {
  union { float f; unsigned u; } v; v.f = f;
  unsigned r = v.u + 0x7FFFu + ((v.u >> 16) & 1u);
  return (unsigned short)(r >> 16);
}
static __device__ __forceinline__ float bf2f(unsigned short h) {
  union { unsigned u; float f; } v; v.u = ((unsigned)h) << 16;
  return v.f;
}

// blocks [0,391): per-chunk coarse histogram of dst>>8 -> hist[cb][chunk] (TRANSPOSED).
// blocks [391,423): Wt[n][k] bf16 combined (k<128: W_gcn, k>=128: W_lin).
// blocks [423,1986): x -> bf16 xb (unscaled).
__global__ __launch_bounds__(256) void k_p0(
    const int* __restrict__ dst, int* __restrict__ hist,
    const float* __restrict__ Wg, const float* __restrict__ Wl,
    unsigned short* __restrict__ Wt, const float4* __restrict__ x4,
    ushort4* __restrict__ xb4) {
  int b = blockIdx.x, t = threadIdx.x;
  if (b < NEBK) {
    __shared__ int cnt[CB];
    for (int i = t; i < CB; i += 256) cnt[i] = 0;
    __syncthreads();
    int e0 = b * EBLK;
    for (int i = t; i < EBLK; i += 256) {
      int e = e0 + i;
      if (e < EE) atomicAdd(&cnt[dst[e] >> 8], 1);
    }
    __syncthreads();
    if (t < CB) {
      hist[t * HST + b] = cnt[t];          // transposed: bucket-major rows
      if (b == 0) hist[t * HST + (HST - 1)] = 0;  // zero the pad column
    }
  } else if (b < NEBK + 32) {
    for (int i = (b - NEBK) * 256 + t; i < DD * 256; i += 32 * 256) {
      int n = i >> 8, k = i & 255;
      float v = (k < 128) ? Wg[k * DD + n] : Wl[(k - 128) * DD + n];
      Wt[i] = f2bf(v);
    }
  } else {
    int base = (b - NEBK - 32) * 1024 + t;
#pragma unroll
    for (int k = 0; k < 4; k++) {
      int i = base + k * 256;
      if (i < NN * 32) {
        float4 v = x4[i];
        ushort4 o;
        o.x = f2bf(v.x); o.y = f2bf(v.y); o.z = f2bf(v.z); o.w = f2bf(v.w);
        xb4[i] = o;
      }
    }
  }
}

// One block per edge chunk: counting-sort the chunk's edges into coarse-bucket
// runs of the global pairs array. Bases self-computed from transposed hist via
// contiguous uint4 row reads (2 threads per bucket). NO global atomics.
// Record: src(16b) | dlocal(8b)<<16 | coarse(8b)<<24.
__global__ __launch_bounds__(512) void k_scatter(
    const int* __restrict__ src, const int* __restrict__ dst,
    const int* __restrict__ hist, int* __restrict__ bucketBase,
    int* __restrict__ bucketTot, unsigned int* __restrict__ pairs) {
  __shared__ unsigned int rec[EBLK];     // 8 KB
  __shared__ unsigned int sorted[EBLK];  // 8 KB
  __shared__ int sTo[2][CB], sCh[2][CB], sOw[2][CB];  // 4.7 KB
  __shared__ unsigned int sc[256];
  __shared__ int cur[CB], gofs[CB];
  int blk = blockIdx.x, t = threadIdx.x;
  int e0 = blk * EBLK;
  int vcnt = EE - e0; if (vcnt > EBLK) vcnt = EBLK;
  // stage records in LDS (chunk order); same thread later re-reads its own slots
  for (int i = t; i < vcnt; i += 512) {
    int d = dst[e0 + i], s = src[e0 + i];
    rec[i] = (unsigned int)s | ((unsigned int)(d & 255) << 16) |
             ((unsigned int)(d >> 8) << 24);
  }
  // vectorized column sums over transposed hist rows: thread (q, half)
  int q = t & 255, h = t >> 8;
  if (q < CB) {
    const uint4* hp = (const uint4*)(hist + (size_t)q * HST + h * (HST / 2));
    int cb0 = h * (HST / 2);
    int to = 0, ch = 0, ow = 0;
#pragma unroll 7
    for (int v = 0; v < HST / 8; ++v) {   // 49 uint4 per half
      uint4 hv = hp[v];
      int c = cb0 + v * 4;
      int a0 = (int)hv.x, a1 = (int)hv.y, a2 = (int)hv.z, a3 = (int)hv.w;
      to += a0 + a1 + a2 + a3;
      ch += (c + 0 < blk ? a0 : 0) + (c + 1 < blk ? a1 : 0) +
            (c + 2 < blk ? a2 : 0) + (c + 3 < blk ? a3 : 0);
      ow += (c + 0 == blk ? a0 : 0) + (c + 1 == blk ? a1 : 0) +
            (c + 2 == blk ? a2 : 0) + (c + 3 == blk ? a3 : 0);
    }
    sTo[h][q] = to; sCh[h][q] = ch; sOw[h][q] = ow;
  }
  __syncthreads();
  int totv = 0, chpv = 0, ownv = 0;
  if (t < CB) {
    totv = sTo[0][t] + sTo[1][t];
    chpv = sCh[0][t] + sCh[1][t];
    ownv = sOw[0][t] + sOw[1][t];
  }
  // single packed scan: (tot<<12)|own  (tot-sum <= 800K < 2^20, own-sum <= 2048)
  if (t < 256) sc[t] = (t < CB) ? (((unsigned)totv << 12) | (unsigned)ownv) : 0u;
  for (int off = 1; off < 256; off <<= 1) {
    __syncthreads();
    unsigned tmp = (t < 256 && t >= off) ? sc[t - off] : 0u;
    __syncthreads();
    if (t < 256 && t >= off) sc[t] += tmp;
  }
  __syncthreads();
  if (t < CB) {
    unsigned v = sc[t];
    int incT = (int)(v >> 12), incO = (int)(v & 4095u);
    int gb = incT - totv;     // bucket global base
    int lo = incO - ownv;     // local sorted base within this chunk
    cur[t] = lo;
    gofs[t] = gb + chpv - lo; // pairs addr of sorted slot i: gofs[cb] + i
    if (blk == 0) { bucketBase[t] = gb; bucketTot[t] = totv; }
  }
  __syncthreads();
  // local counting-sort into LDS (rec[i] re-read by its own writer thread)
  for (int i = t; i < vcnt; i += 512) {
    unsigned int r = rec[i];
    int p = atomicAdd(&cur[r >> 24], 1);
    sorted[p] = r;
  }
  __syncthreads();
  // coalesced write-out (bucket runs contiguous in both LDS and global)
  for (int i = t; i < vcnt; i += 512) {
    unsigned int r = sorted[i];
    pairs[gofs[r >> 24] + i] = r;
  }
}

// One block per coarse bucket: fine histogram from pairs, scan ->
// deg/dinv/rowStart, scatter src -> srcU16. (No xs fold — xs is gone.)
__global__ __launch_bounds__(512) void k_p1b(
    const unsigned int* __restrict__ pairs, const int* __restrict__ bucketBase,
    const int* __restrict__ bucketTot,
    int* __restrict__ deg, float* __restrict__ dinv, int* __restrict__ rowStart,
    unsigned short* __restrict__ srcU16) {
  __shared__ int ldeg[256], lscan[256], lcur[256];
  int b = blockIdx.x, t = threadIdx.x;
  int n0 = b << 8;
  int nloc = NN - n0; if (nloc > 256) nloc = 256;
  int start = bucketBase[b];
  int cnt = bucketTot[b];
  if (t < 256) ldeg[t] = 0;
  __syncthreads();
  for (int i = t; i < cnt; i += 512)
    atomicAdd(&ldeg[(pairs[start + i] >> 16) & 255], 1);
  __syncthreads();
  int dg = (t < 256) ? ldeg[t] : 0;
  if (t < 256) lscan[t] = dg;
  for (int off = 1; off < 256; off <<= 1) {
    __syncthreads();
    int tmp = (t < 256 && t >= off) ? lscan[t - off] : 0;
    __syncthreads();
    if (t < 256 && t >= off) lscan[t] += tmp;
  }
  __syncthreads();
  if (t < 256) {
    int rs = start + lscan[t] - dg;
    lcur[t] = rs;
    if (t < nloc) {
      deg[n0 + t] = dg;
      dinv[n0 + t] = rsqrtf((float)(dg + 1));
      rowStart[n0 + t] = rs;
    }
  }
  __syncthreads();
  for (int i = t; i < cnt; i += 512) {
    unsigned int pr = pairs[start + i];
    int pos = atomicAdd(&lcur[(pr >> 16) & 255], 1);
    srcU16[pos] = (unsigned short)(pr & 0xFFFFu);
  }
}

// Gather a node's CSR range into acc[8] (lane slice r*8), 8 rows in flight.
// Reads UNSCALED xb rows and applies per-edge dinv[src] (shuffled alongside idx).
static __device__ __forceinline__ void gather16(
    const unsigned short* __restrict__ xb, const unsigned short* __restrict__ srcU16,
    const float* __restrict__ dinv,
    int js, int cnt, int r, int srcLaneBase, float* acc) {
  for (int base = 0; base < cnt; base += 16) {
    int idx = (base + r < cnt) ? (int)srcU16[js + base + r] : 0;
    float dv = dinv[idx];
    int m = cnt - base; if (m > 16) m = 16;
    int j = 0;
    for (; j + 8 <= m; j += 8) {
      int s0 = __shfl(idx, srcLaneBase + j);
      int s1 = __shfl(idx, srcLaneBase + j + 1);
      int s2 = __shfl(idx, srcLaneBase + j + 2);
      int s3 = __shfl(idx, srcLaneBase + j + 3);
      int s4 = __shfl(idx, srcLaneBase + j + 4);
      int s5 = __shfl(idx, srcLaneBase + j + 5);
      int s6 = __shfl(idx, srcLaneBase + j + 6);
      int s7 = __shfl(idx, srcLaneBase + j + 7);
      float d0 = __shfl(dv, srcLaneBase + j);
      float d1 = __shfl(dv, srcLaneBase + j + 1);
      float d2 = __shfl(dv, srcLaneBase + j + 2);
      float d3 = __shfl(dv, srcLaneBase + j + 3);
      float d4 = __shfl(dv, srcLaneBase + j + 4);
      float d5 = __shfl(dv, srcLaneBase + j + 5);
      float d6 = __shfl(dv, srcLaneBase + j + 6);
      float d7 = __shfl(dv, srcLaneBase + j + 7);
      bf16x8 v0 = *(const bf16x8*)(xb + (size_t)s0 * DD + r * 8);
      bf16x8 v1 = *(const bf16x8*)(xb + (size_t)s1 * DD + r * 8);
      bf16x8 v2 = *(const bf16x8*)(xb + (size_t)s2 * DD + r * 8);
      bf16x8 v3 = *(const bf16x8*)(xb + (size_t)s3 * DD + r * 8);
      bf16x8 v4 = *(const bf16x8*)(xb + (size_t)s4 * DD + r * 8);
      bf16x8 v5 = *(const bf16x8*)(xb + (size_t)s5 * DD + r * 8);
      bf16x8 v6 = *(const bf16x8*)(xb + (size_t)s6 * DD + r * 8);
      bf16x8 v7 = *(const bf16x8*)(xb + (size_t)s7 * DD + r * 8);
#pragma unroll
      for (int k = 0; k < 8; k++) acc[k] += d0 * bf2f((unsigned short)v0[k]);
#pragma unroll
      for (int k = 0; k < 8; k++) acc[k] += d1 * bf2f((unsigned short)v1[k]);
#pragma unroll
      for (int k = 0; k < 8; k++) acc[k] += d2 * bf2f((unsigned short)v2[k]);
#pragma unroll
      for (int k = 0; k < 8; k++) acc[k] += d3 * bf2f((unsigned short)v3[k]);
#pragma unroll
      for (int k = 0; k < 8; k++) acc[k] += d4 * bf2f((unsigned short)v4[k]);
#pragma unroll
      for (int k = 0; k < 8; k++) acc[k] += d5 * bf2f((unsigned short)v5[k]);
#pragma unroll
      for (int k = 0; k < 8; k++) acc[k] += d6 * bf2f((unsigned short)v6[k]);
#pragma unroll
      for (int k = 0; k < 8; k++) acc[k] += d7 * bf2f((unsigned short)v7[k]);
    }
    for (; j < m; j++) {
      int s = __shfl(idx, srcLaneBase + j);
      float dj = __shfl(dv, srcLaneBase + j);
      bf16x8 v = *(const bf16x8*)(xb + (size_t)s * DD + r * 8);
#pragma unroll
      for (int k = 0; k < 8; k++) acc[k] += dj * bf2f((unsigned short)v[k]);
    }
  }
}

// One block per 32-node bucket, 512 threads: 32 groups x 1 node gather,
// then waves 0-1 run the MFMA [agg|x]@[Wg;Wl] + bias + LayerNorm epilogue.
__global__ __launch_bounds__(512) void k_mega4(
    const unsigned short* __restrict__ xb,
    const int* __restrict__ rowStart, const int* __restrict__ deg,
    const unsigned short* __restrict__ srcU16, const float* __restrict__ dinv,
    const unsigned short* __restrict__ Wt, const float* __restrict__ bgcn,
    const float* __restrict__ lnw, const float* __restrict__ lnb,
    float* __restrict__ out) {
  __shared__ unsigned short abuf[32 * 136];  // 8.7 KB
  int b = blockIdx.x, t = threadIdx.x;
  int n0 = b * 32;
  int g = t >> 4, r = t & 15;
  int lane = t & 63;
  int srcLaneBase = lane & 48;
  int node = n0 + g;
  bool valid = (node < NN);
  int nc = valid ? node : (NN - 1);
  float di = dinv[nc];
  float acc[8];
  {  // self-loop init: dinv[nc] * xb[nc]
    bf16x8 va = *(const bf16x8*)(xb + (size_t)nc * DD + r * 8);
#pragma unroll
    for (int k = 0; k < 8; k++) acc[k] = di * bf2f((unsigned short)va[k]);
  }
  int js = valid ? rowStart[nc] : 0;
  int cnt = valid ? deg[nc] : 0;
  gather16(xb, srcU16, dinv, js, cnt, r, srcLaneBase, acc);
  {
    bf16x8 o;
#pragma unroll
    for (int k = 0; k < 8; k++) o[k] = valid ? (short)f2bf(acc[k] * di) : (short)0;
    *(bf16x8*)&abuf[g * 136 + r * 8] = o;
  }
  __syncthreads();
  if (t < 128) {  // waves 0,1: two 16-row MFMA tiles + fused LayerNorm
    int w = t >> 6, lane2 = t & 63;
    int quad = lane2 >> 4, rr = lane2 & 15;
    int mloc = w * 16 + rr;
    int rowA = n0 + mloc; int rc = (rowA < NN) ? rowA : (NN - 1);
    f32x4 zero = {0.f, 0.f, 0.f, 0.f};
    f32x4 macc[8];
#pragma unroll
    for (int i = 0; i < 8; i++) macc[i] = zero;
#pragma unroll
    for (int ks = 0; ks < 8; ks++) {
      bf16x8 a;
      if (ks < 4) a = *(const bf16x8*)&abuf[mloc * 136 + ks * 32 + quad * 8];
      else        a = *(const bf16x8*)(xb + (size_t)rc * DD + (ks - 4) * 32 + quad * 8);
#pragma unroll
      for (int nt = 0; nt < 8; nt++) {
        bf16x8 bb = *(const bf16x8*)(Wt + (size_t)(nt * 16 + rr) * 256 + ks * 32 + quad * 8);
        macc[nt] = __builtin_amdgcn_mfma_f32_16x16x32_bf16(a, bb, macc[nt], 0, 0, 0);
      }
    }
    float bg[8], lw[8], lb[8];
#pragma unroll
    for (int nt = 0; nt < 8; nt++) {
      int col = nt * 16 + rr;
      bg[nt] = bgcn[col] + 1e-6f;
      lw[nt] = lnw[col];
      lb[nt] = lnb[col];
    }
#pragma unroll
    for (int reg = 0; reg < 4; reg++) {
      float y[8];
      float s1 = 0.f, s2 = 0.f;
#pragma unroll
      for (int nt = 0; nt < 8; nt++) {
        y[nt] = macc[nt][reg] + bg[nt];
        s1 += y[nt];
        s2 += y[nt] * y[nt];
      }
#pragma unroll
      for (int off = 1; off < 16; off <<= 1) {
        s1 += __shfl_xor(s1, off);
        s2 += __shfl_xor(s2, off);
      }
      float mu = s1 * (1.0f / 128.0f);
      float var = s2 * (1.0f / 128.0f) - mu * mu;
      float inv = rsqrtf(var + 1e-5f);
      int row = n0 + w * 16 + quad * 4 + reg;
      if (row < NN) {
#pragma unroll
        for (int nt = 0; nt < 8; nt++) {
          out[(size_t)row * DD + nt * 16 + rr] = (y[nt] - mu) * inv * lw[nt] + lb[nt];
        }
      }
    }
  }
}

extern "C" void kernel_launch(void* const* d_in, const int* in_sizes, int n_in,
                              void* d_out, int out_size, void* d_ws, size_t ws_size,
                              hipStream_t stream) {
  const int* adj = (const int*)d_in[0];
  const float* x = (const float*)d_in[1];
  const float* Wg = (const float*)d_in[2];
  const float* bg = (const float*)d_in[3];
  const float* Wl = (const float*)d_in[4];
  const float* lw = (const float*)d_in[5];
  const float* lb = (const float*)d_in[6];
  const int* srcp = adj;
  const int* dstp = adj + EE;
  float* out = (float*)d_out;

  char* ws = (char*)d_ws;
  size_t off = 0;
  auto alloc = [&](size_t bytes) -> void* {
    void* p = ws + off;
    off += (bytes + 255) & ~(size_t)255;
    return p;
  };
  int* hist = (int*)alloc((size_t)CB * HST * 4);     // transposed, padded
  int* bucketBase = (int*)alloc((size_t)256 * 4);
  int* bucketTot = (int*)alloc((size_t)256 * 4);
  unsigned int* pairs = (unsigned int*)alloc((size_t)EE * 4);
  unsigned short* srcU16 = (unsigned short*)alloc((size_t)EE * 2);
  int* deg = (int*)alloc((size_t)NN * 4);
  float* dinv = (float*)alloc((size_t)NN * 4);
  int* rowStart = (int*)alloc((size_t)NN * 4);
  unsigned short* xb = (unsigned short*)alloc((size_t)NN * DD * 2);
  unsigned short* Wt = (unsigned short*)alloc((size_t)DD * 256 * 2);
  (void)ws_size; (void)in_sizes; (void)n_in; (void)out_size;

  // no memsets: hist columns (incl. pad) fully written by k_p0.
  k_p0<<<NEBK + 32 + 1563, 256, 0, stream>>>(dstp, hist, Wg, Wl, Wt,
                                             (const float4*)x, (ushort4*)xb);
  k_scatter<<<NEBK, 512, 0, stream>>>(srcp, dstp, hist, bucketBase, bucketTot,
                                      pairs);
  k_p1b<<<CB, 512, 0, stream>>>(pairs, bucketBase, bucketTot, deg, dinv,
                                rowStart, srcU16);
  k_mega4<<<NFB, 512, 0, stream>>>(xb, rowStart, deg, srcU16, dinv, Wt,
                                   bg, lw, lb, out);
}

// Round 7
// 189.005 us; speedup vs baseline: 2.2362x; 1.0211x over previous
//
#include <hip/hip_runtime.h>
#include <hip/hip_bf16.h>

#define NN 50000
#define EE 800000
#define DD 128
#define CB 196      // coarse buckets of 256 nodes (196*256 = 50176)
#define NFB 1563    // fine buckets of 32 nodes (mega grid)
#define EBLK 2048
#define NEBK 391    // ceil(EE/EBLK)
#define HST 392     // hist row stride (NEBK padded to multiple of 4)

typedef __attribute__((ext_vector_type(8))) short bf16x8;
typedef __attribute__((ext_vector_type(4))) float f32x4;

static __device__ __forceinline__ unsigned short f2bf(float f) {
  union { float f; unsigned u; } v; v.f = f;
  unsigned r = v.u + 0x7FFFu + ((v.u >> 16) & 1u);
  return (unsigned short)(r >> 16);
}
static __device__ __forceinline__ float bf2f(unsigned short h) {
  union { unsigned u; float f; } v; v.u = ((unsigned)h) << 16;
  return v.f;
}

// blocks [0,391): per-chunk coarse histogram of dst>>8 -> hist[cb][chunk] (TRANSPOSED).
// blocks [391,423): Wt[n][k] bf16 combined (k<128: W_gcn, k>=128: W_lin).
// blocks [423,1986): x -> bf16 xb (unscaled).
__global__ __launch_bounds__(256) void k_p0(
    const int* __restrict__ dst, int* __restrict__ hist,
    const float* __restrict__ Wg, const float* __restrict__ Wl,
    unsigned short* __restrict__ Wt, const float4* __restrict__ x4,
    ushort4* __restrict__ xb4) {
  int b = blockIdx.x, t = threadIdx.x;
  if (b < NEBK) {
    __shared__ int cnt[CB];
    for (int i = t; i < CB; i += 256) cnt[i] = 0;
    __syncthreads();
    int e0 = b * EBLK;
    for (int i = t; i < EBLK; i += 256) {
      int e = e0 + i;
      if (e < EE) atomicAdd(&cnt[dst[e] >> 8], 1);
    }
    __syncthreads();
    if (t < CB) {
      hist[t * HST + b] = cnt[t];          // transposed: bucket-major rows
      if (b == 0) hist[t * HST + (HST - 1)] = 0;  // zero the pad column
    }
  } else if (b < NEBK + 32) {
    for (int i = (b - NEBK) * 256 + t; i < DD * 256; i += 32 * 256) {
      int n = i >> 8, k = i & 255;
      float v = (k < 128) ? Wg[k * DD + n] : Wl[(k - 128) * DD + n];
      Wt[i] = f2bf(v);
    }
  } else {
    int base = (b - NEBK - 32) * 1024 + t;
#pragma unroll
    for (int k = 0; k < 4; k++) {
      int i = base + k * 256;
      if (i < NN * 32) {
        float4 v = x4[i];
        ushort4 o;
        o.x = f2bf(v.x); o.y = f2bf(v.y); o.z = f2bf(v.z); o.w = f2bf(v.w);
        xb4[i] = o;
      }
    }
  }
}

// One block per edge chunk: counting-sort the chunk's edges into coarse-bucket
// runs of the global pairs array. Bases self-computed from transposed hist via
// contiguous uint4 row reads (2 threads per bucket). NO global atomics.
// Record: src(16b) | dlocal(8b)<<16 | coarse(8b)<<24.
__global__ __launch_bounds__(512) void k_scatter(
    const int* __restrict__ src, const int* __restrict__ dst,
    const int* __restrict__ hist, int* __restrict__ bucketBase,
    int* __restrict__ bucketTot, unsigned int* __restrict__ pairs) {
  __shared__ unsigned int rec[EBLK];     // 8 KB
  __shared__ unsigned int sorted[EBLK];  // 8 KB
  __shared__ int sTo[2][CB], sCh[2][CB], sOw[2][CB];  // 4.7 KB
  __shared__ unsigned int sc[256];
  __shared__ int cur[CB], gofs[CB];
  int blk = blockIdx.x, t = threadIdx.x;
  int e0 = blk * EBLK;
  int vcnt = EE - e0; if (vcnt > EBLK) vcnt = EBLK;
  // stage records in LDS (chunk order); same thread later re-reads its own slots
  for (int i = t; i < vcnt; i += 512) {
    int d = dst[e0 + i], s = src[e0 + i];
    rec[i] = (unsigned int)s | ((unsigned int)(d & 255) << 16) |
             ((unsigned int)(d >> 8) << 24);
  }
  // vectorized column sums over transposed hist rows: thread (q, half)
  int q = t & 255, h = t >> 8;
  if (q < CB) {
    const uint4* hp = (const uint4*)(hist + (size_t)q * HST + h * (HST / 2));
    int cb0 = h * (HST / 2);
    int to = 0, ch = 0, ow = 0;
#pragma unroll 7
    for (int v = 0; v < HST / 8; ++v) {   // 49 uint4 per half
      uint4 hv = hp[v];
      int c = cb0 + v * 4;
      int a0 = (int)hv.x, a1 = (int)hv.y, a2 = (int)hv.z, a3 = (int)hv.w;
      to += a0 + a1 + a2 + a3;
      ch += (c + 0 < blk ? a0 : 0) + (c + 1 < blk ? a1 : 0) +
            (c + 2 < blk ? a2 : 0) + (c + 3 < blk ? a3 : 0);
      ow += (c + 0 == blk ? a0 : 0) + (c + 1 == blk ? a1 : 0) +
            (c + 2 == blk ? a2 : 0) + (c + 3 == blk ? a3 : 0);
    }
    sTo[h][q] = to; sCh[h][q] = ch; sOw[h][q] = ow;
  }
  __syncthreads();
  int totv = 0, chpv = 0, ownv = 0;
  if (t < CB) {
    totv = sTo[0][t] + sTo[1][t];
    chpv = sCh[0][t] + sCh[1][t];
    ownv = sOw[0][t] + sOw[1][t];
  }
  // single packed scan: (tot<<12)|own  (tot-sum <= 800K < 2^20, own-sum <= 2048)
  if (t < 256) sc[t] = (t < CB) ? (((unsigned)totv << 12) | (unsigned)ownv) : 0u;
  for (int off = 1; off < 256; off <<= 1) {
    __syncthreads();
    unsigned tmp = (t < 256 && t >= off) ? sc[t - off] : 0u;
    __syncthreads();
    if (t < 256 && t >= off) sc[t] += tmp;
  }
  __syncthreads();
  if (t < CB) {
    unsigned v = sc[t];
    int incT = (int)(v >> 12), incO = (int)(v & 4095u);
    int gb = incT - totv;     // bucket global base
    int lo = incO - ownv;     // local sorted base within this chunk
    cur[t] = lo;
    gofs[t] = gb + chpv - lo; // pairs addr of sorted slot i: gofs[cb] + i
    if (blk == 0) { bucketBase[t] = gb; bucketTot[t] = totv; }
  }
  __syncthreads();
  // local counting-sort into LDS (rec[i] re-read by its own writer thread)
  for (int i = t; i < vcnt; i += 512) {
    unsigned int r = rec[i];
    int p = atomicAdd(&cur[r >> 24], 1);
    sorted[p] = r;
  }
  __syncthreads();
  // coalesced write-out (bucket runs contiguous in both LDS and global)
  for (int i = t; i < vcnt; i += 512) {
    unsigned int r = sorted[i];
    pairs[gofs[r >> 24] + i] = r;
  }
}

// One block per coarse bucket: fine histogram from pairs, scan ->
// deg/dinv/rowStart, scatter src -> srcU16, and xs = dinv*xb fold.
__global__ __launch_bounds__(512) void k_p1b(
    const unsigned int* __restrict__ pairs, const int* __restrict__ bucketBase,
    const int* __restrict__ bucketTot, const unsigned short* __restrict__ xb,
    int* __restrict__ deg, float* __restrict__ dinv, int* __restrict__ rowStart,
    unsigned short* __restrict__ srcU16, unsigned short* __restrict__ xs) {
  __shared__ int ldeg[256], lscan[256], lcur[256];
  __shared__ float ldinvs[256];
  int b = blockIdx.x, t = threadIdx.x;
  int n0 = b << 8;
  int nloc = NN - n0; if (nloc > 256) nloc = 256;
  int start = bucketBase[b];
  int cnt = bucketTot[b];
  if (t < 256) ldeg[t] = 0;
  __syncthreads();
  for (int i = t; i < cnt; i += 512)
    atomicAdd(&ldeg[(pairs[start + i] >> 16) & 255], 1);
  __syncthreads();
  int dg = (t < 256) ? ldeg[t] : 0;
  if (t < 256) lscan[t] = dg;
  for (int off = 1; off < 256; off <<= 1) {
    __syncthreads();
    int tmp = (t < 256 && t >= off) ? lscan[t - off] : 0;
    __syncthreads();
    if (t < 256 && t >= off) lscan[t] += tmp;
  }
  __syncthreads();
  if (t < 256) {
    int rs = start + lscan[t] - dg;
    lcur[t] = rs;
    float di = rsqrtf((float)(dg + 1));
    ldinvs[t] = di;
    if (t < nloc) { deg[n0 + t] = dg; dinv[n0 + t] = di; rowStart[n0 + t] = rs; }
  }
  __syncthreads();
  for (int i = t; i < cnt; i += 512) {
    unsigned int pr = pairs[start + i];
    int pos = atomicAdd(&lcur[(pr >> 16) & 255], 1);
    srcU16[pos] = (unsigned short)(pr & 0xFFFFu);
  }
  // xs fold: scale this bucket's rows (independent of scatter above)
  for (int i = t; i < nloc * 16; i += 512) {
    int rr = i >> 4, qq = i & 15;
    bf16x8 v = *(const bf16x8*)(xb + (size_t)(n0 + rr) * DD + qq * 8);
    float di = ldinvs[rr];
    bf16x8 o;
#pragma unroll
    for (int k = 0; k < 8; k++) o[k] = (short)f2bf(bf2f((unsigned short)v[k]) * di);
    *(bf16x8*)(xs + (size_t)(n0 + rr) * DD + qq * 8) = o;
  }
}

// Gather a node's CSR range into acc[8] (lane slice r*8), 8 rows in flight.
static __device__ __forceinline__ void gather16(
    const unsigned short* __restrict__ xs, const unsigned short* __restrict__ srcU16,
    int js, int cnt, int r, int srcLaneBase, float* acc) {
  for (int base = 0; base < cnt; base += 16) {
    int idx = (base + r < cnt) ? (int)srcU16[js + base + r] : 0;
    int m = cnt - base; if (m > 16) m = 16;
    int j = 0;
    for (; j + 8 <= m; j += 8) {
      int s0 = __shfl(idx, srcLaneBase + j);
      int s1 = __shfl(idx, srcLaneBase + j + 1);
      int s2 = __shfl(idx, srcLaneBase + j + 2);
      int s3 = __shfl(idx, srcLaneBase + j + 3);
      int s4 = __shfl(idx, srcLaneBase + j + 4);
      int s5 = __shfl(idx, srcLaneBase + j + 5);
      int s6 = __shfl(idx, srcLaneBase + j + 6);
      int s7 = __shfl(idx, srcLaneBase + j + 7);
      bf16x8 v0 = *(const bf16x8*)(xs + (size_t)s0 * DD + r * 8);
      bf16x8 v1 = *(const bf16x8*)(xs + (size_t)s1 * DD + r * 8);
      bf16x8 v2 = *(const bf16x8*)(xs + (size_t)s2 * DD + r * 8);
      bf16x8 v3 = *(const bf16x8*)(xs + (size_t)s3 * DD + r * 8);
      bf16x8 v4 = *(const bf16x8*)(xs + (size_t)s4 * DD + r * 8);
      bf16x8 v5 = *(const bf16x8*)(xs + (size_t)s5 * DD + r * 8);
      bf16x8 v6 = *(const bf16x8*)(xs + (size_t)s6 * DD + r * 8);
      bf16x8 v7 = *(const bf16x8*)(xs + (size_t)s7 * DD + r * 8);
#pragma unroll
      for (int k = 0; k < 8; k++) acc[k] += bf2f((unsigned short)v0[k]);
#pragma unroll
      for (int k = 0; k < 8; k++) acc[k] += bf2f((unsigned short)v1[k]);
#pragma unroll
      for (int k = 0; k < 8; k++) acc[k] += bf2f((unsigned short)v2[k]);
#pragma unroll
      for (int k = 0; k < 8; k++) acc[k] += bf2f((unsigned short)v3[k]);
#pragma unroll
      for (int k = 0; k < 8; k++) acc[k] += bf2f((unsigned short)v4[k]);
#pragma unroll
      for (int k = 0; k < 8; k++) acc[k] += bf2f((unsigned short)v5[k]);
#pragma unroll
      for (int k = 0; k < 8; k++) acc[k] += bf2f((unsigned short)v6[k]);
#pragma unroll
      for (int k = 0; k < 8; k++) acc[k] += bf2f((unsigned short)v7[k]);
    }
    for (; j < m; j++) {
      int s = __shfl(idx, srcLaneBase + j);
      bf16x8 v = *(const bf16x8*)(xs + (size_t)s * DD + r * 8);
#pragma unroll
      for (int k = 0; k < 8; k++) acc[k] += bf2f((unsigned short)v[k]);
    }
  }
}

// One block per 32-node bucket, 512 threads: 32 groups x 1 node gather, then
// ALL 8 waves run the MFMA epilogue: wave w -> (rowTile = w&1, colPair = w>>1,
// i.e. 16 rows x 32 cols, 16 MFMA). LayerNorm row-sums are combined across the
// 4 col-waves via an LDS partial table (deterministic two-stage reduction).
__global__ __launch_bounds__(512) void k_mega5(
    const unsigned short* __restrict__ xs, const unsigned short* __restrict__ xb,
    const int* __restrict__ rowStart, const int* __restrict__ deg,
    const unsigned short* __restrict__ srcU16, const float* __restrict__ dinv,
    const unsigned short* __restrict__ Wt, const float* __restrict__ bgcn,
    const float* __restrict__ lnw, const float* __restrict__ lnb,
    float* __restrict__ out) {
  __shared__ unsigned short abuf[32 * 136];  // 8.7 KB
  __shared__ float lnred[4][32][2];          // 1 KB: per-colPair row partials
  int b = blockIdx.x, t = threadIdx.x;
  int n0 = b * 32;
  int g = t >> 4, r = t & 15;
  int lane = t & 63;
  int srcLaneBase = lane & 48;
  int node = n0 + g;
  bool valid = (node < NN);
  int nc = valid ? node : (NN - 1);
  float acc[8];
  {  // self-loop init from pre-scaled xs
    bf16x8 va = *(const bf16x8*)(xs + (size_t)nc * DD + r * 8);
#pragma unroll
    for (int k = 0; k < 8; k++) acc[k] = bf2f((unsigned short)va[k]);
  }
  int js = valid ? rowStart[nc] : 0;
  int cnt = valid ? deg[nc] : 0;
  gather16(xs, srcU16, js, cnt, r, srcLaneBase, acc);
  {
    float d = dinv[nc];
    bf16x8 o;
#pragma unroll
    for (int k = 0; k < 8; k++) o[k] = valid ? (short)f2bf(acc[k] * d) : (short)0;
    *(bf16x8*)&abuf[g * 136 + r * 8] = o;
  }
  __syncthreads();
  // ---- all-wave epilogue ----
  int w = t >> 6, lane2 = t & 63;
  int quad = lane2 >> 4, rr = lane2 & 15;
  int rowTile = w & 1, colPair = w >> 1;   // 2 row-tiles x 4 col-pairs
  int mloc = rowTile * 16 + rr;
  int rowA = n0 + mloc; int rc = (rowA < NN) ? rowA : (NN - 1);
  f32x4 zero = {0.f, 0.f, 0.f, 0.f};
  f32x4 macc[2];
  macc[0] = zero; macc[1] = zero;
#pragma unroll
  for (int ks = 0; ks < 8; ks++) {
    bf16x8 a;
    if (ks < 4) a = *(const bf16x8*)&abuf[mloc * 136 + ks * 32 + quad * 8];
    else        a = *(const bf16x8*)(xb + (size_t)rc * DD + (ks - 4) * 32 + quad * 8);
#pragma unroll
    for (int j = 0; j < 2; j++) {
      int nt = colPair * 2 + j;
      bf16x8 bb = *(const bf16x8*)(Wt + (size_t)(nt * 16 + rr) * 256 + ks * 32 + quad * 8);
      macc[j] = __builtin_amdgcn_mfma_f32_16x16x32_bf16(a, bb, macc[j], 0, 0, 0);
    }
  }
  float bg[2], lw[2], lb[2];
#pragma unroll
  for (int j = 0; j < 2; j++) {
    int col = (colPair * 2 + j) * 16 + rr;
    bg[j] = bgcn[col] + 1e-6f;
    lw[j] = lnw[col];
    lb[j] = lnb[col];
  }
  // partial LN sums: each wave covers 32 of 128 cols for its 16 rows
#pragma unroll
  for (int reg = 0; reg < 4; reg++) {
    float y0 = macc[0][reg] + bg[0];
    float y1 = macc[1][reg] + bg[1];
    float s1 = y0 + y1, s2 = y0 * y0 + y1 * y1;
#pragma unroll
    for (int off = 1; off < 16; off <<= 1) {
      s1 += __shfl_xor(s1, off);
      s2 += __shfl_xor(s2, off);
    }
    if (rr == 0) {
      int rloc = rowTile * 16 + quad * 4 + reg;
      lnred[colPair][rloc][0] = s1;
      lnred[colPair][rloc][1] = s2;
    }
  }
  __syncthreads();
#pragma unroll
  for (int reg = 0; reg < 4; reg++) {
    int rloc = rowTile * 16 + quad * 4 + reg;
    float s1 = lnred[0][rloc][0] + lnred[1][rloc][0] +
               lnred[2][rloc][0] + lnred[3][rloc][0];
    float s2 = lnred[0][rloc][1] + lnred[1][rloc][1] +
               lnred[2][rloc][1] + lnred[3][rloc][1];
    float mu = s1 * (1.0f / 128.0f);
    float var = s2 * (1.0f / 128.0f) - mu * mu;
    float inv = rsqrtf(var + 1e-5f);
    int row = n0 + rloc;
    if (row < NN) {
#pragma unroll
      for (int j = 0; j < 2; j++) {
        float y = macc[j][reg] + bg[j];
        out[(size_t)row * DD + (colPair * 2 + j) * 16 + rr] =
            (y - mu) * inv * lw[j] + lb[j];
      }
    }
  }
}

extern "C" void kernel_launch(void* const* d_in, const int* in_sizes, int n_in,
                              void* d_out, int out_size, void* d_ws, size_t ws_size,
                              hipStream_t stream) {
  const int* adj = (const int*)d_in[0];
  const float* x = (const float*)d_in[1];
  const float* Wg = (const float*)d_in[2];
  const float* bg = (const float*)d_in[3];
  const float* Wl = (const float*)d_in[4];
  const float* lw = (const float*)d_in[5];
  const float* lb = (const float*)d_in[6];
  const int* srcp = adj;
  const int* dstp = adj + EE;
  float* out = (float*)d_out;

  char* ws = (char*)d_ws;
  size_t off = 0;
  auto alloc = [&](size_t bytes) -> void* {
    void* p = ws + off;
    off += (bytes + 255) & ~(size_t)255;
    return p;
  };
  int* hist = (int*)alloc((size_t)CB * HST * 4);     // transposed, padded
  int* bucketBase = (int*)alloc((size_t)256 * 4);
  int* bucketTot = (int*)alloc((size_t)256 * 4);
  unsigned int* pairs = (unsigned int*)alloc((size_t)EE * 4);
  unsigned short* srcU16 = (unsigned short*)alloc((size_t)EE * 2);
  int* deg = (int*)alloc((size_t)NN * 4);
  float* dinv = (float*)alloc((size_t)NN * 4);
  int* rowStart = (int*)alloc((size_t)NN * 4);
  unsigned short* xb = (unsigned short*)alloc((size_t)NN * DD * 2);
  unsigned short* xs = (unsigned short*)alloc((size_t)NN * DD * 2);
  unsigned short* Wt = (unsigned short*)alloc((size_t)DD * 256 * 2);
  (void)ws_size; (void)in_sizes; (void)n_in; (void)out_size;

  // no memsets: hist columns (incl. pad) fully written by k_p0.
  k_p0<<<NEBK + 32 + 1563, 256, 0, stream>>>(dstp, hist, Wg, Wl, Wt,
                                             (const float4*)x, (ushort4*)xb);
  k_scatter<<<NEBK, 512, 0, stream>>>(srcp, dstp, hist, bucketBase, bucketTot,
                                      pairs);
  k_p1b<<<CB, 512, 0, stream>>>(pairs, bucketBase, bucketTot, xb, deg, dinv,
                                rowStart, srcU16, xs);
  k_mega5<<<NFB, 512, 0, stream>>>(xs, xb, rowStart, deg, srcU16, dinv, Wt,
                                   bg, lw, lb, out);
}